// Round 1
// 853.932 us; speedup vs baseline: 1.2686x; 1.2686x over previous
//
#include <hip/hip_runtime.h>
#include <hip/hip_bf16.h>
#include <math.h>

typedef __bf16 bf16_t;
typedef float f32x4 __attribute__((ext_vector_type(4)));
typedef __bf16 bf16x8 __attribute__((ext_vector_type(8)));
typedef __bf16 bf16x4 __attribute__((ext_vector_type(4)));
typedef int i32x4 __attribute__((ext_vector_type(4)));

#define SCALING 0.17677669529663687f
#define LNEPS 1e-5f

// ws layout (bytes); total = 224,002,176 (vt lives in d_out)
#define OFF_QKG   0u            // bf16 [131072][768]: q | k | gate; q-region reused for gated AV out
#define OFF_LOG   201326592u    // f32  [8][512][512]: attn logits
#define OFF_BIAS  209715200u    // f32  [8][512][512]: pair bias
#define OFF_P     218103808u    // bf16 [8][512][512]: softmax probs
#define OFF_WT    222298112u    // bf16 [1024][256]  : [wq|wk|wv|wg]^T, K-chunk XOR-swizzled
#define OFF_WTO   222822400u    // bf16 [256][256]   : w_out^T
#define OFF_FLAG  222953472u    // int: 1 if inputs are fp32, 0 if bf16

#define GLOBAL_AS __attribute__((address_space(1)))
#define LDS_AS    __attribute__((address_space(3)))

static __device__ __forceinline__ f32x4 mfma16(bf16x8 a, bf16x8 b, f32x4 c) {
  return __builtin_amdgcn_mfma_f32_16x16x32_bf16(a, b, c, 0, 0, 0);
}

static __device__ __forceinline__ float ldf(const void* p, int i, int is32) {
  return is32 ? ((const float*)p)[i] : (float)((const bf16_t*)p)[i];
}
static __device__ __forceinline__ float scrubf(float x) {
  if (x != x) return 0.f;
  return fminf(fmaxf(x, -3.3e38f), 3.3e38f);
}

// ---------------- K-1: detect input dtype ----------------
__global__ __launch_bounds__(256) void k_detect(const unsigned short* raw, int* flag) {
  __shared__ int s;
  int t = threadIdx.x;
  if (t == 0) s = 0;
  __syncthreads();
  int local = 0;
  for (int i = 0; i < 16; i++) {
    unsigned short u = raw[t * 16 + i];
    int e = (u >> 7) & 0xFF;
    if (e >= 170) local = 1;   // |x| >= 2^43 as bf16: impossible for N(0,1) bf16 data
  }
  if (local) s = 1;
  __syncthreads();
  if (t == 0) *flag = s;
}

// ---------------- K0: transpose weights (any dtype -> bf16) ----------------
// wt_cat stores column c's K-row with 16B chunks XOR-swizzled: element k goes to
// index k ^ ((c&7)<<3). k_proj stages these tiles linearly via global_load_lds and
// reads fragments with the same XOR -> bank-conflict-free ds_read_b128.
__global__ __launch_bounds__(256) void k_transpose(
    const void* wq, const void* wk, const void* wv, const void* wg,
    const void* wout, const int* flag, bf16_t* wt_cat, bf16_t* wt_out) {
  int is32 = *flag;
  int idx = blockIdx.x * 256 + threadIdx.x;
  if (idx < 1024 * 256) {
    int c = idx >> 8, k = idx & 255;
    const void* src = (c < 256) ? wq : (c < 512) ? wk : (c < 768) ? wv : wg;
    wt_cat[c * 256 + (k ^ ((c & 7) << 3))] = (bf16_t)ldf(src, k * 256 + (c & 255), is32);
  } else {
    int i2 = idx - 1024 * 256;  // < 65536
    int c = i2 >> 8, k = i2 & 255;
    wt_out[c * 256 + k] = (bf16_t)ldf(wout, k * 256 + c, is32);
  }
}

// ---------------- K2: pair LN + @ w_b -> bias[h][q][k] (f32) ----------------
__global__ __launch_bounds__(256) void k_pair_bias(
    const void* pair, const void* g, const void* b,
    const void* wb, const int* flag, float* bias_ws) {
  __shared__ float wbs[128 * 8];  // wb[c][h]
  __shared__ float gs[128], bs[128];
  int is32 = *flag;
  int t = threadIdx.x;
  if (t < 128) { gs[t] = ldf(g, t, is32); bs[t] = ldf(b, t, is32); }
  for (int i = t; i < 1024; i += 256) wbs[i] = ldf(wb, i, is32);
  __syncthreads();
  int lane = t & 63, w = t >> 6;
  int j = lane & 7;        // element-group within row (16 elems each)
  int rowg = lane >> 3;    // row within pass (0..7)
  float gr[16], br[16];
#pragma unroll
  for (int e = 0; e < 16; e++) { gr[e] = gs[j * 16 + e]; br[e] = bs[j * 16 + e]; }
  int row0 = blockIdx.x * 64 + w * 16;
#pragma unroll
  for (int pass = 0; pass < 2; pass++) {
    int row = row0 + pass * 8 + rowg;
    float x[16];
    if (is32) {
#pragma unroll
      for (int i = 0; i < 4; i++) {
        f32x4 v = *(const f32x4*)((const float*)pair + (size_t)row * 128 + j * 16 + i * 4);
#pragma unroll
        for (int e = 0; e < 4; e++) x[i * 4 + e] = scrubf(v[e]);
      }
    } else {
#pragma unroll
      for (int i = 0; i < 2; i++) {
        i32x4 raw = *(const i32x4*)((const bf16_t*)pair + (size_t)row * 128 + j * 16 + i * 8);
        const bf16_t* sp = (const bf16_t*)&raw;
#pragma unroll
        for (int e = 0; e < 8; e++) x[i * 8 + e] = scrubf((float)sp[e]);
      }
    }
    float s = 0.f, sq = 0.f;
#pragma unroll
    for (int e = 0; e < 16; e++) { s += x[e]; sq += x[e] * x[e]; }
#pragma unroll
    for (int o = 1; o <= 4; o <<= 1) {
      s += __shfl_xor(s, o, 64);
      sq += __shfl_xor(sq, o, 64);
    }
    float mu = s * (1.f / 128.f);
    float var = sq * (1.f / 128.f) - mu * mu;
    float rs = rsqrtf(fmaxf(var, 0.f) + LNEPS);
    float ph[8] = {0.f, 0.f, 0.f, 0.f, 0.f, 0.f, 0.f, 0.f};
#pragma unroll
    for (int e = 0; e < 16; e++) {
      float xn = (x[e] - mu) * rs * gr[e] + br[e];
      const float* wp = wbs + (j * 16 + e) * 8;
      f32x4 w0 = *(const f32x4*)wp;
      f32x4 w1 = *(const f32x4*)(wp + 4);
#pragma unroll
      for (int hh = 0; hh < 4; hh++) { ph[hh] += xn * w0[hh]; ph[4 + hh] += xn * w1[hh]; }
    }
#pragma unroll
    for (int o = 1; o <= 4; o <<= 1) {
#pragma unroll
      for (int hh = 0; hh < 8; hh++) ph[hh] += __shfl_xor(ph[hh], o, 64);
    }
    if (j == 0) {
      int qp = row >> 9, kp = row & 511;
      float* bp = bias_ws + (size_t)qp * 512 + kp;
#pragma unroll
      for (int hh = 0; hh < 8; hh++) bp[(size_t)hh * 262144] = ph[hh];
    }
  }
}

// ---------------- K3: QKVG projection GEMM ----------------
// 1024 blocks x 512 threads. Per block: 128-row A tile LN-staged to LDS ONCE
// (stats fused in-kernel), A-frags held in 128 VGPRs, then all 8 column tiles
// computed with B half-tiles streamed via global_load_lds (double-buffered;
// buf1 overlaps the dead As region). wt_cat is pre-swizzled so ds_read_b128
// of B frags is conflict-free.
static __device__ __forceinline__ void issue_b(const bf16_t* wtc, int col0, int half,
                                               char* dst, int t) {
#pragma unroll
  for (int j = 0; j < 4; ++j) {
    int o = t * 16 + j * 8192;           // 0..32752
    int row = o >> 8, within = o & 255;  // 256 B per half-row
    const char* src = (const char*)wtc + (size_t)(col0 + row) * 512 + half * 256 + within;
    __builtin_amdgcn_global_load_lds((const GLOBAL_AS void*)src,
                                     (LDS_AS void*)(dst + o), 16, 0, 0);
  }
}

__global__ __launch_bounds__(512) void k_proj(
    const void* msa, const void* lng, const void* lnb,
    const bf16_t* wt_cat, const void* bg, const int* mask, const int* flag,
    bf16_t* qkg, bf16_t* vt) {
  __shared__ __align__(16) char lds[100352];
  bf16_t* As = (bf16_t*)lds;        // [128][264] bf16 = 67584 B
  char* buf0 = lds + 67584;         // B half-tile [128][128] bf16 = 32768 B
  char* buf1 = lds;                 // overlaps As (dead after a-frag load)
  int is32 = *flag;
  int t = threadIdx.x, lane = t & 63, w = t >> 6;
  int wr = w & 1, wc = w >> 1;      // wave tile: 64 rows x 32 cols
  int hi = lane >> 4, cl = lane & 15;
  int row0 = blockIdx.x * 128;

  // ---- stage A tile with fused LN (stats via 4-lane shfl reduce) ----
  {
    int ar = t >> 2;            // row 0..127 (4 threads/row)
    int ac = (t & 3) << 6;      // 64-col quarter
    float xv[64];
    if (is32) {
      const float* xr = (const float*)msa + (size_t)(row0 + ar) * 256 + ac;
#pragma unroll
      for (int i = 0; i < 16; ++i) {
        f32x4 v = *(const f32x4*)(xr + i * 4);
#pragma unroll
        for (int e = 0; e < 4; ++e) xv[i * 4 + e] = scrubf(v[e]);
      }
    } else {
      const bf16_t* xr = (const bf16_t*)msa + (size_t)(row0 + ar) * 256 + ac;
#pragma unroll
      for (int i = 0; i < 8; ++i) {
        i32x4 raw = *(const i32x4*)(xr + i * 8);
        const bf16_t* sp = (const bf16_t*)&raw;
#pragma unroll
        for (int e = 0; e < 8; ++e) xv[i * 8 + e] = scrubf((float)sp[e]);
      }
    }
    float s = 0.f, sq = 0.f;
#pragma unroll
    for (int i = 0; i < 64; ++i) { s += xv[i]; sq += xv[i] * xv[i]; }
    s += __shfl_xor(s, 1, 64); sq += __shfl_xor(sq, 1, 64);
    s += __shfl_xor(s, 2, 64); sq += __shfl_xor(sq, 2, 64);
    float mu = s * (1.f / 256.f);
    float var = sq * (1.f / 256.f) - mu * mu;
    float rs = rsqrtf(fmaxf(var, 0.f) + LNEPS);
    if (is32) {
      const float* gp = (const float*)lng + ac;
      const float* bp = (const float*)lnb + ac;
#pragma unroll
      for (int i = 0; i < 16; ++i) {
        f32x4 g = *(const f32x4*)(gp + i * 4);
        f32x4 b = *(const f32x4*)(bp + i * 4);
        bf16x4 y;
#pragma unroll
        for (int e = 0; e < 4; ++e)
          y[e] = (bf16_t)((xv[i * 4 + e] - mu) * rs * g[e] + b[e]);
        *(bf16x4*)(As + (size_t)ar * 264 + ac + i * 4) = y;
      }
    } else {
      const bf16_t* gp = (const bf16_t*)lng + ac;
      const bf16_t* bp = (const bf16_t*)lnb + ac;
#pragma unroll
      for (int i = 0; i < 8; ++i) {
        i32x4 gr = *(const i32x4*)(gp + i * 8);
        i32x4 br = *(const i32x4*)(bp + i * 8);
        const bf16_t* gs = (const bf16_t*)&gr;
        const bf16_t* bs = (const bf16_t*)&br;
        bf16x8 y;
#pragma unroll
        for (int e = 0; e < 8; ++e)
          y[e] = (bf16_t)((xv[i * 8 + e] - mu) * rs * (float)gs[e] + (float)bs[e]);
        *(bf16x8*)(As + (size_t)ar * 264 + ac + i * 8) = y;
      }
    }
  }
  __syncthreads();                       // As ready
  issue_b(wt_cat, 0, 0, buf0, t);        // prefetch (bn0, half0)

  bf16x8 aall[8][4];                     // full-K A fragments: 128 VGPRs
  {
    int arow = wr * 64 + cl;
#pragma unroll
    for (int ks = 0; ks < 8; ++ks)
#pragma unroll
      for (int m = 0; m < 4; ++m)
        aall[ks][m] = *(const bf16x8*)(As + (size_t)(arow + m * 16) * 264 + ks * 32 + hi * 8);
  }
  __syncthreads();                       // a-frags read + prefetch landed

  int brow0 = wc * 32 + cl, brow1 = brow0 + 16;
  int rbase = row0 + wr * 64 + hi * 4;
  unsigned padbits = 0;
#pragma unroll
  for (int m = 0; m < 4; ++m)
#pragma unroll
    for (int i = 0; i < 4; ++i)
      if (mask[(rbase + m * 16 + i) & 511] == 0) padbits |= 1u << (m * 4 + i);

  f32x4 z = {0.f, 0.f, 0.f, 0.f};
  f32x4 acc[4][2] = {{z, z}, {z, z}, {z, z}, {z, z}};

  for (int bn = 0; bn < 8; ++bn) {
    issue_b(wt_cat, bn << 7, 1, buf1, t);   // prefetch this bn's half1
#pragma unroll
    for (int kk = 0; kk < 4; ++kk) {        // half0 from buf0 (ks 0..3)
      int k8 = kk * 4 + hi;
      bf16x8 b0 = *(const bf16x8*)(buf0 + brow0 * 256 + ((k8 ^ (brow0 & 7)) << 4));
      bf16x8 b1 = *(const bf16x8*)(buf0 + brow1 * 256 + ((k8 ^ (brow1 & 7)) << 4));
#pragma unroll
      for (int m = 0; m < 4; ++m) {
        acc[m][0] = mfma16(aall[kk][m], b0, acc[m][0]);
        acc[m][1] = mfma16(aall[kk][m], b1, acc[m][1]);
      }
    }
    __syncthreads();                        // half1 landed; buf0 free
    if (bn < 7) issue_b(wt_cat, (bn + 1) << 7, 0, buf0, t);  // prefetch next half0
#pragma unroll
    for (int kk = 0; kk < 4; ++kk) {        // half1 from buf1 (ks 4..7)
      int k8 = kk * 4 + hi;
      bf16x8 b0 = *(const bf16x8*)(buf1 + brow0 * 256 + ((k8 ^ (brow0 & 7)) << 4));
      bf16x8 b1 = *(const bf16x8*)(buf1 + brow1 * 256 + ((k8 ^ (brow1 & 7)) << 4));
#pragma unroll
      for (int m = 0; m < 4; ++m) {
        acc[m][0] = mfma16(aall[4 + kk][m], b0, acc[m][0]);
        acc[m][1] = mfma16(aall[4 + kk][m], b1, acc[m][1]);
      }
    }
    __syncthreads();                        // next half0 landed; buf1 free
    // epilogue for bn (after barrier: stores drain under next bn's MFMA phase)
    int region = bn >> 1;
    int col0 = bn << 7;
#pragma unroll
    for (int m = 0; m < 4; ++m) {
#pragma unroll
      for (int n = 0; n < 2; ++n) {
        int col = col0 + wc * 32 + n * 16 + cl;
#pragma unroll
        for (int i = 0; i < 4; ++i) {
          int r = rbase + m * 16 + i;
          bool pad = (padbits >> (m * 4 + i)) & 1;
          float v = acc[m][n][i];
          if (region == 0) {
            qkg[(size_t)r * 768 + col] = (bf16_t)(pad ? 0.f : v);
          } else if (region == 1) {
            qkg[(size_t)r * 768 + col] = (bf16_t)(pad ? 0.f : v * SCALING);
          } else if (region == 2) {
            int hd = col & 255;
            vt[((size_t)((r >> 9) * 8 + (hd >> 5)) * 32 + (hd & 31)) * 512 + (r & 511)] =
                (bf16_t)(pad ? 0.f : v);
          } else {
            int gcol = col & 255;
            float xg = v + ldf(bg, gcol, is32);
            qkg[(size_t)r * 768 + 512 + gcol] = (bf16_t)(1.f / (1.f + __expf(-xg)));
          }
          acc[m][n][i] = 0.f;
        }
      }
    }
  }
}

// ---------------- K4: logits[h][q][k] = sum_{n,d} q*k ----------------
__global__ __launch_bounds__(256) void k_logits(const bf16_t* qkg, float* logit_ws) {
  __shared__ bf16_t As[64 * 136];
  __shared__ bf16_t Bs[64 * 136];
  int t = threadIdx.x, lane = t & 63, w = t >> 6;
  // XCD-grouped decode: all 64 (qtile,ktile) blocks of a head land on one XCD,
  // ktile innermost within it -> A-tile L2 reuse actually works.
  int j = blockIdx.x;
  int jj = (j & 7) * 64 + (j >> 3);
  int ktile = jj & 7, qtile = (jj >> 3) & 7, h = jj >> 6;
  int mw = w & 1, nw = w >> 1;
  f32x4 z = {0.f, 0.f, 0.f, 0.f};
  f32x4 acc[2][2] = {{z, z}, {z, z}};
  for (int s = 0; s < 64; s++) {
    int kk0 = s * 128;
#pragma unroll
    for (int i = 0; i < 4; i++) {
      int flat = t + i * 256;  // 1024 chunks
      int r = flat >> 4, c8 = flat & 15;
      int kk = kk0 + c8 * 8;
      int n = kk >> 5, d = kk & 31;
      i32x4 va = *(const i32x4*)(qkg + ((size_t)(n * 512 + qtile * 64 + r)) * 768 + h * 32 + d);
      *(i32x4*)(As + r * 136 + c8 * 8) = va;
      i32x4 vb = *(const i32x4*)(qkg + ((size_t)(n * 512 + ktile * 64 + r)) * 768 + 256 + h * 32 + d);
      *(i32x4*)(Bs + r * 136 + c8 * 8) = vb;
    }
    __syncthreads();
#pragma unroll
    for (int kk = 0; kk < 128; kk += 32) {
      int ko = kk + (lane >> 4) * 8;
      bf16x8 a0 = *(const bf16x8*)(As + (mw * 32 + (lane & 15)) * 136 + ko);
      bf16x8 a1 = *(const bf16x8*)(As + (mw * 32 + 16 + (lane & 15)) * 136 + ko);
      bf16x8 b0 = *(const bf16x8*)(Bs + (nw * 32 + (lane & 15)) * 136 + ko);
      bf16x8 b1 = *(const bf16x8*)(Bs + (nw * 32 + 16 + (lane & 15)) * 136 + ko);
      acc[0][0] = mfma16(a0, b0, acc[0][0]);
      acc[0][1] = mfma16(a0, b1, acc[0][1]);
      acc[1][0] = mfma16(a1, b0, acc[1][0]);
      acc[1][1] = mfma16(a1, b1, acc[1][1]);
    }
    __syncthreads();
  }
  int quad = lane >> 4, cl = lane & 15;
#pragma unroll
  for (int mt = 0; mt < 2; mt++) {
#pragma unroll
    for (int nt = 0; nt < 2; nt++) {
      int kp = ktile * 64 + nw * 32 + nt * 16 + cl;
#pragma unroll
      for (int i = 0; i < 4; i++) {
        int q = qtile * 64 + mw * 32 + mt * 16 + quad * 4 + i;
        logit_ws[((size_t)(h * 512 + q)) * 512 + kp] = acc[mt][nt][i];
      }
    }
  }
}

// ---------------- K5: softmax over k with bias + 2D mask ----------------
__global__ __launch_bounds__(256) void k_softmax(
    const float* logit_ws, const float* bias_ws, const int* mask, bf16_t* p_ws) {
  __shared__ float red[8];
  int t = threadIdx.x;
  int hq = blockIdx.x;  // h*512 + q
  int q = hq & 511;
  bool padq = (mask[q] == 0);
  const float* lg = logit_ws + (size_t)hq * 512;
  const float* bi = bias_ws + (size_t)(hq >> 9) * 262144 + (size_t)q * 512;
  int k0 = t * 2;
  float v0 = lg[k0] + bi[k0];
  float v1 = lg[k0 + 1] + bi[k0 + 1];
  if (padq || mask[k0] == 0) v0 = -1e9f;
  if (padq || mask[k0 + 1] == 0) v1 = -1e9f;
  float m = fmaxf(v0, v1);
#pragma unroll
  for (int o = 32; o >= 1; o >>= 1) m = fmaxf(m, __shfl_xor(m, o, 64));
  if ((t & 63) == 0) red[t >> 6] = m;
  __syncthreads();
  m = fmaxf(fmaxf(red[0], red[1]), fmaxf(red[2], red[3]));
  float e0 = __expf(v0 - m), e1 = __expf(v1 - m);
  float s = e0 + e1;
#pragma unroll
  for (int o = 32; o >= 1; o >>= 1) s += __shfl_xor(s, o, 64);
  if ((t & 63) == 0) red[4 + (t >> 6)] = s;
  __syncthreads();
  s = red[4] + red[5] + red[6] + red[7];
  float inv = 1.f / s;
  p_ws[(size_t)hq * 512 + k0] = (bf16_t)(e0 * inv);
  p_ws[(size_t)hq * 512 + k0 + 1] = (bf16_t)(e1 * inv);
}

// ---------------- K6: O = P @ V, * gate -> q-region of qkg ----------------
__global__ __launch_bounds__(256) void k_av(
    const bf16_t* p_ws, const bf16_t* vt, bf16_t* qkg) {
  __shared__ bf16_t Ps[64 * 136];
  __shared__ bf16_t Vs[32 * 136];
  int t = threadIdx.x, lane = t & 63, w = t >> 6;
  // XCD-grouped decode: one head per XCD, qt innermost -> V-tile reused 8x in
  // that XCD's L2 instead of refetched; P[h] (512KB) stays L2-resident.
  int j = blockIdx.x;
  int jj = (j & 7) * 2048 + (j >> 3);
  int qt = jj & 7;
  int n = (jj >> 3) & 255;
  int h = jj >> 11;
  f32x4 z = {0.f, 0.f, 0.f, 0.f};
  f32x4 acc[2] = {z, z};
  for (int s = 0; s < 4; s++) {
    int k0 = s * 128;
#pragma unroll
    for (int i = 0; i < 4; i++) {
      int flat = t + i * 256;
      int r = flat >> 4, c8 = flat & 15;
      *(i32x4*)(Ps + r * 136 + c8 * 8) =
          *(const i32x4*)(p_ws + ((size_t)(h * 512 + qt * 64 + r)) * 512 + k0 + c8 * 8);
    }
#pragma unroll
    for (int i = 0; i < 2; i++) {
      int flat = t + i * 256;
      int r = flat >> 4, c8 = flat & 15;  // r = d
      *(i32x4*)(Vs + r * 136 + c8 * 8) =
          *(const i32x4*)(vt + ((size_t)((n * 8 + h) * 32 + r)) * 512 + k0 + c8 * 8);
    }
    __syncthreads();
#pragma unroll
    for (int kk = 0; kk < 128; kk += 32) {
      int ko = kk + (lane >> 4) * 8;
      bf16x8 a = *(const bf16x8*)(Ps + (w * 16 + (lane & 15)) * 136 + ko);
      bf16x8 b0 = *(const bf16x8*)(Vs + ((lane & 15)) * 136 + ko);
      bf16x8 b1 = *(const bf16x8*)(Vs + (16 + (lane & 15)) * 136 + ko);
      acc[0] = mfma16(a, b0, acc[0]);
      acc[1] = mfma16(a, b1, acc[1]);
    }
    __syncthreads();
  }
  int quad = lane >> 4, cl = lane & 15;
#pragma unroll
  for (int nt = 0; nt < 2; nt++) {
#pragma unroll
    for (int i = 0; i < 4; i++) {
      int q = qt * 64 + w * 16 + quad * 4 + i;
      int d = nt * 16 + cl;
      size_t base = ((size_t)(n * 512 + q)) * 768;
      float gate = (float)qkg[base + 512 + h * 32 + d];
      qkg[base + h * 32 + d] = (bf16_t)(acc[nt][i] * gate);
    }
  }
}

// ---------------- K7: out = gated @ w_out + b_out, pad-zeroed ----------------
__global__ __launch_bounds__(256) void k_out(
    const bf16_t* qkg, const bf16_t* wt_out, const void* b_out,
    const int* mask, const int* flag, void* outp) {
  __shared__ bf16_t As[64 * 72];
  __shared__ bf16_t Bs[64 * 72];
  int is32 = *flag;
  int t = threadIdx.x, lane = t & 63, w = t >> 6;
  int bm = blockIdx.x >> 2, bn = blockIdx.x & 3;
  int row0 = bm * 64;
  int mw = w & 1, nw = w >> 1;
  f32x4 z = {0.f, 0.f, 0.f, 0.f};
  f32x4 acc[2][2] = {{z, z}, {z, z}};
  for (int kt = 0; kt < 4; kt++) {
#pragma unroll
    for (int i = 0; i < 2; i++) {
      int flat = t + i * 256;
      int r = flat >> 3, c8 = flat & 7;
      *(i32x4*)(As + r * 72 + c8 * 8) =
          *(const i32x4*)(qkg + (size_t)(row0 + r) * 768 + kt * 64 + c8 * 8);
      *(i32x4*)(Bs + r * 72 + c8 * 8) =
          *(const i32x4*)(wt_out + (size_t)(bn * 64 + r) * 256 + kt * 64 + c8 * 8);
    }
    __syncthreads();
#pragma unroll
    for (int kk = 0; kk < 64; kk += 32) {
      int ko = kk + (lane >> 4) * 8;
      bf16x8 a0 = *(const bf16x8*)(As + (mw * 32 + (lane & 15)) * 72 + ko);
      bf16x8 a1 = *(const bf16x8*)(As + (mw * 32 + 16 + (lane & 15)) * 72 + ko);
      bf16x8 b0 = *(const bf16x8*)(Bs + (nw * 32 + (lane & 15)) * 72 + ko);
      bf16x8 b1 = *(const bf16x8*)(Bs + (nw * 32 + 16 + (lane & 15)) * 72 + ko);
      acc[0][0] = mfma16(a0, b0, acc[0][0]);
      acc[0][1] = mfma16(a0, b1, acc[0][1]);
      acc[1][0] = mfma16(a1, b0, acc[1][0]);
      acc[1][1] = mfma16(a1, b1, acc[1][1]);
    }
    __syncthreads();
  }
  int quad = lane >> 4, cl = lane & 15;
#pragma unroll
  for (int mt = 0; mt < 2; mt++) {
#pragma unroll
    for (int nt = 0; nt < 2; nt++) {
      int col = bn * 64 + nw * 32 + nt * 16 + cl;
      float bo = ldf(b_out, col, is32);
#pragma unroll
      for (int i = 0; i < 4; i++) {
        int r = row0 + mw * 32 + mt * 16 + quad * 4 + i;
        int l = r & 511;
        float v = acc[mt][nt][i] + bo;
        if (mask[l] == 0) v = 0.f;
        if (is32) ((float*)outp)[(size_t)r * 256 + col] = v;
        else ((bf16_t*)outp)[(size_t)r * 256 + col] = (bf16_t)v;
      }
    }
  }
}

extern "C" void kernel_launch(void* const* d_in, const int* in_sizes, int n_in,
                              void* d_out, int out_size, void* d_ws, size_t ws_size,
                              hipStream_t stream) {
  const void* msa      = d_in[0];
  const void* pair     = d_in[1];
  const void* ln_msa_g = d_in[2];
  const void* ln_msa_b = d_in[3];
  const void* ln_pair_g= d_in[4];
  const void* ln_pair_b= d_in[5];
  const void* w_q      = d_in[6];
  const void* w_k      = d_in[7];
  const void* w_v      = d_in[8];
  const void* w_b      = d_in[9];
  const void* w_g      = d_in[10];
  const void* b_g      = d_in[11];
  const void* w_out    = d_in[12];
  const void* b_out    = d_in[13];
  const int*  mask     = (const int*)d_in[14];

  char* ws = (char*)d_ws;
  bf16_t* qkg   = (bf16_t*)(ws + OFF_QKG);
  float*  logit = (float*)(ws + OFF_LOG);
  float*  biasb = (float*)(ws + OFF_BIAS);
  bf16_t* pbuf  = (bf16_t*)(ws + OFF_P);
  bf16_t* wtc   = (bf16_t*)(ws + OFF_WT);
  bf16_t* wto   = (bf16_t*)(ws + OFF_WTO);
  int*    flag  = (int*)(ws + OFF_FLAG);
  bf16_t* vt    = (bf16_t*)d_out;  // dead before k_out writes final output

  k_detect<<<1, 256, 0, stream>>>((const unsigned short*)msa, flag);
  k_transpose<<<1280, 256, 0, stream>>>(w_q, w_k, w_v, w_g, w_out, flag, wtc, wto);
  k_pair_bias<<<4096, 256, 0, stream>>>(pair, ln_pair_g, ln_pair_b, w_b, flag, biasb);
  k_proj<<<1024, 512, 0, stream>>>(msa, ln_msa_g, ln_msa_b, wtc, b_g, mask, flag, qkg, vt);
  k_logits<<<512, 256, 0, stream>>>(qkg, logit);
  k_softmax<<<4096, 256, 0, stream>>>(logit, biasb, mask, pbuf);
  k_av<<<16384, 256, 0, stream>>>(pbuf, vt, qkg);
  k_out<<<8192, 256, 0, stream>>>(qkg, wto, b_out, mask, flag, d_out);
}